// Round 4
// baseline (818.835 us; speedup 1.0000x reference)
//
#include <hip/hip_runtime.h>
#include <hip/hip_fp16.h>

#define N_NODES 100000
#define N_EDGES 1600000
#define NFEAT   256
#define NHID    128
#define LATENT  64
#define NBUCKET 782          // ceil(N_NODES / 128)

typedef __attribute__((ext_vector_type(8))) short s16x8;
typedef __attribute__((ext_vector_type(4))) float f32x4;

__device__ __forceinline__ unsigned short f2bf(float f) {
    union { float f; unsigned u; } v; v.f = f;
    unsigned r = v.u + 0x7fffu + ((v.u >> 16) & 1u);   // RNE (finite inputs)
    return (unsigned short)(r >> 16);
}
__device__ __forceinline__ float bf2f(unsigned short s) {
    union { unsigned u; float f; } v; v.u = ((unsigned)s) << 16;
    return v.f;
}
// edge weight in [0,1): fp16 sans sign bit = 15 bits
__device__ __forceinline__ float w15_decode(unsigned pv) {
    return __half2float(__ushort_as_half((unsigned short)(pv & 0x7fffu)));
}

// ---------------------------------------------------------------- scans

__global__ __launch_bounds__(512) void k_scan1(const int* __restrict__ deg,
                                               int* __restrict__ row_ptr,
                                               int* __restrict__ bsum) {
    __shared__ int s[2][512];
    int t = threadIdx.x;
    int i = blockIdx.x * 512 + t;
    int v = (i < N_NODES) ? deg[i] : 0;
    s[0][t] = v;
    __syncthreads();
    int p = 0;
    for (int off = 1; off < 512; off <<= 1) {
        int x = s[p][t];
        if (t >= off) x += s[p][t - off];
        s[p ^ 1][t] = x;
        p ^= 1;
        __syncthreads();
    }
    int incl = s[p][t];
    if (i < N_NODES) row_ptr[i] = incl - v;
    if (t == 511) bsum[blockIdx.x] = incl;
}

__global__ __launch_bounds__(256) void k_scan2(int* __restrict__ bsum, int nb) {
    __shared__ int s[2][256];
    int t = threadIdx.x;
    int v = (t < nb) ? bsum[t] : 0;
    s[0][t] = v;
    __syncthreads();
    int p = 0;
    for (int off = 1; off < 256; off <<= 1) {
        int x = s[p][t];
        if (t >= off) x += s[p][t - off];
        s[p ^ 1][t] = x;
        p ^= 1;
        __syncthreads();
    }
    if (t < nb) bsum[t] = s[p][t] - v;
}

__global__ __launch_bounds__(512) void k_scan3(int* __restrict__ row_ptr,
                                               const int* __restrict__ bsum,
                                               int* __restrict__ bcursor) {
    int i = blockIdx.x * 512 + threadIdx.x;
    if (i < N_NODES) {
        int v = row_ptr[i] + bsum[blockIdx.x];
        row_ptr[i] = v;
        if ((i & 127) == 0) bcursor[i >> 7] = v;   // coarse-bucket base
    }
    if (blockIdx.x == 0 && threadIdx.x == 0) row_ptr[N_NODES] = N_EDGES;
}

// ------------------------------------------------------- weight pre-convert
// fp32 [K][N] (optionally split at ncol0 between B0/B1) -> bf16 in MFMA
// fragment-block order: out[((nt*K8 + kc)*16 + m)*8 + j] = B[kc*8+j][nt*16+m]

__device__ __forceinline__ void prep_body(
    int c, int K, int Ntot, int ncol0, int ldb0, int ldb1,
    const float* __restrict__ B0, const float* __restrict__ B1,
    unsigned short* __restrict__ out)
{
    int K8 = K >> 3;
    int total = (Ntot >> 4) * K8 * 16;
    if (c >= total) return;
    int m  = c & 15;
    int kc = (c >> 4) % K8;
    int nt = (c >> 4) / K8;
    int col = nt * 16 + m;
    const float* src; int ld, cc;
    if (col < ncol0) { src = B0; ld = ldb0; cc = col; }
    else             { src = B1; ld = ldb1; cc = col - ncol0; }
    s16x8 v;
    #pragma unroll
    for (int j = 0; j < 8; ++j)
        v[j] = (short)f2bf(src[(size_t)(kc * 8 + j) * ld + cc]);
    *(s16x8*)&out[(size_t)c * 8] = v;
}

// ---------------------------------------------------------------- fused pre:
// degree histogram (6250 blocks) || prep w1/w2/w3 (32 blocks)

__global__ __launch_bounds__(256) void k_pre(
    const int* __restrict__ rows, int* __restrict__ deg,
    const float* __restrict__ gc1_w, unsigned short* __restrict__ w1p,
    const float* __restrict__ gc2_w, unsigned short* __restrict__ w2p,
    const float* __restrict__ mu_w, const float* __restrict__ lv_w,
    unsigned short* __restrict__ w3p)
{
    int b = blockIdx.x;
    int t = threadIdx.x;
    if (b < 6250) {
        atomicAdd(&deg[rows[b * 256 + t]], 1);
    } else if (b < 6266) {
        prep_body((b - 6250) * 256 + t, NFEAT, NHID, NHID, NHID, NHID, gc1_w, gc1_w, w1p);
    } else if (b < 6274) {
        prep_body((b - 6266) * 256 + t, NHID, NHID, NHID, NHID, NHID, gc2_w, gc2_w, w2p);
    } else {
        prep_body((b - 6274) * 256 + t, NHID, NHID, LATENT, LATENT, LATENT, mu_w, lv_w, w3p);
    }
}

// --------------------------------------------------- radix scatter, pass A
// 782 coarse buckets (row>>7); only ~782 hot destination lines -> writes
// coalesce into full 64B lines in L2 (vs 1.6M random-line dirties before).

__global__ __launch_bounds__(256) void k_passA(
    const int* __restrict__ rows, const int* __restrict__ cols,
    const float* __restrict__ ew, int* __restrict__ bcursor,
    uint2* __restrict__ tmp)
{
    int e = blockIdx.x * 256 + threadIdx.x;
    int r = rows[e];
    unsigned hv = (unsigned)__half_as_ushort(__float2half(ew[e]));
    unsigned pv = ((unsigned)cols[e] << 15) | (hv & 0x7fffu);
    int p = atomicAdd(&bcursor[r >> 7], 1);
    tmp[p] = make_uint2(pv, (unsigned)r);
}

// --------------------------------------------------- radix scatter, pass B
// one block per bucket; per-row cursors in LDS; destination is the bucket's
// ~8KB contiguous CSR slice (L2-resident, full-line writeback).

__global__ __launch_bounds__(256) void k_passB(
    const int* __restrict__ row_ptr, const uint2* __restrict__ tmp,
    unsigned* __restrict__ ecw)
{
    __shared__ int cur[128];
    int b  = blockIdx.x;
    int r0 = b * 128;
    int t  = threadIdx.x;
    if (t < 128) {
        int rr = r0 + t;
        cur[t] = (rr < N_NODES) ? row_ptr[rr] : N_EDGES;
    }
    __syncthreads();
    int beg = row_ptr[r0];
    int rend = r0 + 128; if (rend > N_NODES) rend = N_NODES;
    int end = row_ptr[rend];
    for (int e = beg + t; e < end; e += 256) {
        uint2 v = tmp[e];
        int p = atomicAdd(&cur[v.y & 127], 1);
        ecw[p] = v.x;
    }
}

// ---------------------------------------------------------------- MFMA GEMM
// C[M x 128] = A[M x K] @ B[K x 128], bf16 MFMA 16x16x32, fp32 accumulate.
// BM=32 BN=128 BK=64, 256 threads = 4 waves. AMODE 0: A fp32 (convert while
// staging); AMODE 1: A bf16 row-major stride 128. OMODE 0: C bf16 row-major;
// OMODE 1: fp32 split at col 64 into C0/C1 with fused bias.

template<int AMODE, int OMODE>
__global__ __launch_bounds__(256) void k_gemm(
    int K, const float* __restrict__ A32, const unsigned short* __restrict__ A16,
    const unsigned short* __restrict__ Bpre,
    unsigned short* __restrict__ C16,
    float* __restrict__ C0, float* __restrict__ C1,
    const float* __restrict__ bias0, const float* __restrict__ bias1)
{
    __shared__ unsigned short As[2048];  // [rt2][kc8][m16][j8]
    __shared__ unsigned short Bs[8192];  // [nt8][kc8][n16][j8]

    const int t    = threadIdx.x;
    const int m0   = blockIdx.x * 32;
    const int lane = t & 63;
    const int w    = t >> 6;
    const int rt   = w & 1;
    const int ntb  = (w >> 1) * 4;
    const int fm   = lane & 15;
    const int q    = lane >> 4;
    const int K8   = K >> 3;

    f32x4 acc[4] = {};

    for (int kt = 0; kt < K; kt += 64) {
        {
            int r = t >> 3, kc = t & 7;
            int lo = ((r >> 4) * 8 + kc) * 128 + (r & 15) * 8;
            if (AMODE == 0) {
                const float* g = A32 + (size_t)(m0 + r) * K + kt + kc * 8;
                float4 a = *(const float4*)g;
                float4 b = *(const float4*)(g + 4);
                s16x8 v;
                v[0] = (short)f2bf(a.x); v[1] = (short)f2bf(a.y);
                v[2] = (short)f2bf(a.z); v[3] = (short)f2bf(a.w);
                v[4] = (short)f2bf(b.x); v[5] = (short)f2bf(b.y);
                v[6] = (short)f2bf(b.z); v[7] = (short)f2bf(b.w);
                *(s16x8*)&As[lo] = v;
            } else {
                const unsigned short* g = A16 + (size_t)(m0 + r) * 128 + kt + kc * 8;
                *(s16x8*)&As[lo] = *(const s16x8*)g;
            }
        }
        {
            int ktc = kt >> 3;
            #pragma unroll
            for (int i = 0; i < 4; ++i) {
                int c  = t + i * 256;
                int nt = c >> 7, kc = (c >> 4) & 7, m = c & 15;
                const unsigned short* g =
                    Bpre + ((size_t)(nt * K8 + ktc + kc) * 16 + m) * 8;
                *(s16x8*)&Bs[c * 8] = *(const s16x8*)g;
            }
        }
        __syncthreads();
        #pragma unroll
        for (int kk = 0; kk < 2; ++kk) {
            int kcq = kk * 4 + q;
            s16x8 a = *(const s16x8*)&As[(rt * 8 + kcq) * 128 + fm * 8];
            #pragma unroll
            for (int i = 0; i < 4; ++i) {
                s16x8 b = *(const s16x8*)&Bs[((ntb + i) * 8 + kcq) * 128 + fm * 8];
                acc[i] = __builtin_amdgcn_mfma_f32_16x16x32_bf16(a, b, acc[i], 0, 0, 0);
            }
        }
        __syncthreads();
    }

    // epilogue: C/D layout col=lane&15, row=q*4+reg
    #pragma unroll
    for (int i = 0; i < 4; ++i) {
        int col = (ntb + i) * 16 + fm;
        #pragma unroll
        for (int j = 0; j < 4; ++j) {
            int r = m0 + rt * 16 + q * 4 + j;
            float v = acc[i][j];
            if (OMODE == 0) {
                C16[(size_t)r * 128 + col] = f2bf(v);
            } else {
                if (col < 64) C0[(size_t)r * 64 + col]      = v + bias0[col];
                else          C1[(size_t)r * 64 + col - 64] = v + bias1[col - 64];
            }
        }
    }
}

// ---------------------------------------------------------------- SpMM gather
// out[row] = relu(bias + sum_e w_e * sup[col_e]); sup/out bf16, fp32 accum.
// One wave per row; lane-halves own edge parity (2 edges / load instr),
// 32 lanes x uint2 = 4 bf16 feats per lane; unroll 4 -> 8 gathers in flight.
// Cross-half combine via shfl_xor(32).

__global__ __launch_bounds__(256) void k_spmm(const int* __restrict__ row_ptr,
                                              const unsigned* __restrict__ ecw,
                                              const unsigned short* __restrict__ sup,
                                              const float* __restrict__ bias,
                                              unsigned short* __restrict__ out) {
    int wave = threadIdx.x >> 6;
    int lane = threadIdx.x & 63;
    int row  = blockIdx.x * 4 + wave;
    if (row >= N_NODES) return;
    int half = lane >> 5;          // edge parity
    int fl   = lane & 31;          // feats fl*4 .. fl*4+3

    int beg = row_ptr[row];
    int end = row_ptr[row + 1];
    float a0 = 0.f, a1 = 0.f, a2 = 0.f, a3 = 0.f;

    int n8 = beg + ((end - beg) & ~7);
    for (int e = beg; e < n8; e += 8) {
        unsigned q0 = ecw[e + 0 + half];
        unsigned q1 = ecw[e + 2 + half];
        unsigned q2 = ecw[e + 4 + half];
        unsigned q3 = ecw[e + 6 + half];
        uint2 v0 = *(const uint2*)(sup + (size_t)(q0 >> 15) * NHID + fl * 4);
        uint2 v1 = *(const uint2*)(sup + (size_t)(q1 >> 15) * NHID + fl * 4);
        uint2 v2 = *(const uint2*)(sup + (size_t)(q2 >> 15) * NHID + fl * 4);
        uint2 v3 = *(const uint2*)(sup + (size_t)(q3 >> 15) * NHID + fl * 4);
        float w0 = w15_decode(q0), w1 = w15_decode(q1);
        float w2 = w15_decode(q2), w3 = w15_decode(q3);
        a0 += w0 * bf2f((unsigned short)v0.x);
        a1 += w0 * bf2f((unsigned short)(v0.x >> 16));
        a2 += w0 * bf2f((unsigned short)v0.y);
        a3 += w0 * bf2f((unsigned short)(v0.y >> 16));
        a0 += w1 * bf2f((unsigned short)v1.x);
        a1 += w1 * bf2f((unsigned short)(v1.x >> 16));
        a2 += w1 * bf2f((unsigned short)v1.y);
        a3 += w1 * bf2f((unsigned short)(v1.y >> 16));
        a0 += w2 * bf2f((unsigned short)v2.x);
        a1 += w2 * bf2f((unsigned short)(v2.x >> 16));
        a2 += w2 * bf2f((unsigned short)v2.y);
        a3 += w2 * bf2f((unsigned short)(v2.y >> 16));
        a0 += w3 * bf2f((unsigned short)v3.x);
        a1 += w3 * bf2f((unsigned short)(v3.x >> 16));
        a2 += w3 * bf2f((unsigned short)v3.y);
        a3 += w3 * bf2f((unsigned short)(v3.y >> 16));
    }
    for (int e = n8; e < end; e += 2) {
        int ee = e + half;
        if (ee < end) {
            unsigned q = ecw[ee];
            uint2 v = *(const uint2*)(sup + (size_t)(q >> 15) * NHID + fl * 4);
            float w = w15_decode(q);
            a0 += w * bf2f((unsigned short)v.x);
            a1 += w * bf2f((unsigned short)(v.x >> 16));
            a2 += w * bf2f((unsigned short)v.y);
            a3 += w * bf2f((unsigned short)(v.y >> 16));
        }
    }
    a0 += __shfl_xor(a0, 32, 64);
    a1 += __shfl_xor(a1, 32, 64);
    a2 += __shfl_xor(a2, 32, 64);
    a3 += __shfl_xor(a3, 32, 64);

    if (half == 0) {
        float o0 = a0 + bias[fl * 4 + 0];
        float o1 = a1 + bias[fl * 4 + 1];
        float o2 = a2 + bias[fl * 4 + 2];
        float o3 = a3 + bias[fl * 4 + 3];
        o0 = o0 > 0.f ? o0 : 0.f;
        o1 = o1 > 0.f ? o1 : 0.f;
        o2 = o2 > 0.f ? o2 : 0.f;
        o3 = o3 > 0.f ? o3 : 0.f;
        uint2 pv;
        pv.x = (unsigned)f2bf(o0) | ((unsigned)f2bf(o1) << 16);
        pv.y = (unsigned)f2bf(o2) | ((unsigned)f2bf(o3) << 16);
        *(uint2*)(out + (size_t)row * NHID + fl * 4) = pv;
    }
}

// ---------------------------------------------------------------- launch

extern "C" void kernel_launch(void* const* d_in, const int* in_sizes, int n_in,
                              void* d_out, int out_size, void* d_ws, size_t ws_size,
                              hipStream_t stream) {
    const float* x     = (const float*)d_in[0];
    const int*   ei    = (const int*)  d_in[1];
    const float* ew    = (const float*)d_in[2];
    const float* gc1_w = (const float*)d_in[3];
    const float* gc1_b = (const float*)d_in[4];
    const float* gc2_w = (const float*)d_in[5];
    const float* gc2_b = (const float*)d_in[6];
    const float* mu_w  = (const float*)d_in[7];
    const float* mu_b  = (const float*)d_in[8];
    const float* lv_w  = (const float*)d_in[9];
    const float* lv_b  = (const float*)d_in[10];
    float* out = (float*)d_out;

    const int* rows = ei;
    const int* cols = ei + N_EDGES;

    char* p = (char*)d_ws;
    auto alloc = [&](size_t bytes) {
        char* r = p;
        p += (bytes + 255) & ~(size_t)255;
        return r;
    };
    int*      deg     = (int*)     alloc((size_t)N_NODES * 4);
    int*      row_ptr = (int*)     alloc((size_t)(N_NODES + 1) * 4);
    int*      bcursor = (int*)     alloc((size_t)NBUCKET * 4);
    int*      bsum    = (int*)     alloc(1024);
    unsigned* ecw     = (unsigned*)alloc((size_t)N_EDGES * 4);
    uint2*    tmp     = (uint2*)   alloc((size_t)N_EDGES * 8);
    unsigned short* w1p    = (unsigned short*)alloc((size_t)NFEAT * NHID * 2);
    unsigned short* w2p    = (unsigned short*)alloc((size_t)NHID * NHID * 2);
    unsigned short* w3p    = (unsigned short*)alloc((size_t)NHID * NHID * 2);
    unsigned short* bufSup = (unsigned short*)alloc((size_t)N_NODES * NHID * 2);
    unsigned short* bufH   = (unsigned short*)alloc((size_t)N_NODES * NHID * 2);
    (void)ws_size; (void)n_in; (void)in_sizes; (void)out_size;

    const int nbScan = (N_NODES + 511) / 512;   // 196

    hipMemsetAsync(deg, 0, (size_t)N_NODES * 4, stream);
    // count || prep w1/w2/w3
    k_pre<<<6250 + 32, 256, 0, stream>>>(rows, deg, gc1_w, w1p, gc2_w, w2p,
                                         mu_w, lv_w, w3p);
    k_scan1<<<nbScan, 512, 0, stream>>>(deg, row_ptr, bsum);
    k_scan2<<<1, 256, 0, stream>>>(bsum, nbScan);
    k_scan3<<<nbScan, 512, 0, stream>>>(row_ptr, bsum, bcursor);
    // two-pass radix edge reorder
    k_passA<<<6250, 256, 0, stream>>>(rows, cols, ew, bcursor, tmp);
    k_passB<<<NBUCKET, 256, 0, stream>>>(row_ptr, tmp, ecw);

    // gc1
    k_gemm<0, 0><<<N_NODES / 32, 256, 0, stream>>>(NFEAT, x, nullptr, w1p,
                                                   bufSup, nullptr, nullptr, nullptr, nullptr);
    k_spmm<<<N_NODES / 4, 256, 0, stream>>>(row_ptr, ecw, bufSup, gc1_b, bufH);
    // gc2
    k_gemm<1, 0><<<N_NODES / 32, 256, 0, stream>>>(NHID, nullptr, bufH, w2p,
                                                   bufSup, nullptr, nullptr, nullptr, nullptr);
    k_spmm<<<N_NODES / 4, 256, 0, stream>>>(row_ptr, ecw, bufSup, gc2_b, bufH);
    // mu / log_var fused projection
    k_gemm<1, 1><<<N_NODES / 32, 256, 0, stream>>>(NHID, nullptr, bufH, w3p,
                                                   nullptr, out, out + (size_t)N_NODES * LATENT,
                                                   mu_b, lv_b);
}

// Round 5
// 485.942 us; speedup vs baseline: 1.6850x; 1.6850x over previous
//
#include <hip/hip_runtime.h>
#include <hip/hip_fp16.h>

#define N_NODES 100000
#define N_EDGES 1600000
#define NFEAT   256
#define NHID    128
#define LATENT  64

#define NBUCKET 782              // ceil(N_NODES / 128), 128 rows per bucket
#define NBLKH   196              // histogram/scatter blocks
#define CHUNK   8192             // edges per histogram/scatter block
#define NHIST   (NBUCKET * NBLKH)   // 153272
#define NROWT   196              // row-scan tiles of 512
#define NHISTT  300              // hist-scan tiles of 512 (300*512 >= NHIST)

typedef __attribute__((ext_vector_type(8))) short s16x8;
typedef __attribute__((ext_vector_type(4))) float f32x4;

__device__ __forceinline__ unsigned short f2bf(float f) {
    union { float f; unsigned u; } v; v.f = f;
    unsigned r = v.u + 0x7fffu + ((v.u >> 16) & 1u);   // RNE (finite inputs)
    return (unsigned short)(r >> 16);
}
__device__ __forceinline__ float bf2f(unsigned short s) {
    union { unsigned u; float f; } v; v.u = ((unsigned)s) << 16;
    return v.f;
}
// edge weight in [0,1): fp16 sans sign bit = 15 bits
__device__ __forceinline__ float w15_decode(unsigned pv) {
    return __half2float(__ushort_as_half((unsigned short)(pv & 0x7fffu)));
}

// inclusive 512-wide block scan (ping-pong); block-uniform call sites only
__device__ __forceinline__ int incl_scan512(int v, int t, int (&s)[2][512]) {
    s[0][t] = v;
    __syncthreads();
    int p = 0;
    for (int off = 1; off < 512; off <<= 1) {
        int x = s[p][t];
        if (t >= off) x += s[p][t - off];
        s[p ^ 1][t] = x;
        p ^= 1;
        __syncthreads();
    }
    return s[p][t];
}

// ------------------------------------------------------- weight pre-convert
// fp32 [K][N] (optionally split at ncol0 between B0/B1) -> bf16 in MFMA
// fragment-block order: out[((nt*K8 + kc)*16 + m)*8 + j] = B[kc*8+j][nt*16+m]

__device__ __forceinline__ void prep_body(
    int c, int K, int Ntot, int ncol0, int ldb0, int ldb1,
    const float* __restrict__ B0, const float* __restrict__ B1,
    unsigned short* __restrict__ out)
{
    int K8 = K >> 3;
    int total = (Ntot >> 4) * K8 * 16;
    if (c >= total) return;
    int m  = c & 15;
    int kc = (c >> 4) % K8;
    int nt = (c >> 4) / K8;
    int col = nt * 16 + m;
    const float* src; int ld, cc;
    if (col < ncol0) { src = B0; ld = ldb0; cc = col; }
    else             { src = B1; ld = ldb1; cc = col - ncol0; }
    s16x8 v;
    #pragma unroll
    for (int j = 0; j < 8; ++j)
        v[j] = (short)f2bf(src[(size_t)(kc * 8 + j) * ld + cc]);
    *(s16x8*)&out[(size_t)c * 8] = v;
}

// ---------------------------------------------------------------- k_pre:
// blocks 0..195: per-chunk degree count (global, spread over 100k addrs)
//                + LDS coarse-bucket histogram -> histG[bucket][block]
// blocks 196+ : weight pre-convert w1/w2/w3

__global__ __launch_bounds__(256) void k_pre(
    const int* __restrict__ rows, int* __restrict__ deg,
    int* __restrict__ histG,
    const float* __restrict__ gc1_w, unsigned short* __restrict__ w1p,
    const float* __restrict__ gc2_w, unsigned short* __restrict__ w2p,
    const float* __restrict__ mu_w, const float* __restrict__ lv_w,
    unsigned short* __restrict__ w3p)
{
    int b = blockIdx.x;
    int t = threadIdx.x;
    if (b < NBLKH) {
        __shared__ int hist[NBUCKET];
        for (int i = t; i < NBUCKET; i += 256) hist[i] = 0;
        __syncthreads();
        int base = b * CHUNK;
        #pragma unroll 4
        for (int i = 0; i < CHUNK / 256; ++i) {
            int e = base + i * 256 + t;
            if (e < N_EDGES) {
                int r = rows[e];
                atomicAdd(&deg[r], 1);
                atomicAdd(&hist[r >> 7], 1);
            }
        }
        __syncthreads();
        for (int i = t; i < NBUCKET; i += 256)
            histG[(size_t)i * NBLKH + b] = hist[i];
    } else if (b < NBLKH + 16) {
        prep_body((b - NBLKH) * 256 + t, NFEAT, NHID, NHID, NHID, NHID, gc1_w, gc1_w, w1p);
    } else if (b < NBLKH + 24) {
        prep_body((b - NBLKH - 16) * 256 + t, NHID, NHID, NHID, NHID, NHID, gc2_w, gc2_w, w2p);
    } else {
        prep_body((b - NBLKH - 24) * 256 + t, NHID, NHID, LATENT, LATENT, LATENT, mu_w, lv_w, w3p);
    }
}

// ---------------------------------------------------------------- scans
// A: per-512-tile exclusive scans of deg (196 tiles) and histG (300 tiles)
// B: scan the two block-sum arrays (196 and 300 entries)
// C: add-back -> row_ptr (+ tail) and scanned hist

__global__ __launch_bounds__(512) void k_scanA(
    const int* __restrict__ deg, int* __restrict__ row_excl, int* __restrict__ rbsum,
    const int* __restrict__ histG, int* __restrict__ hist_excl, int* __restrict__ hbsum)
{
    __shared__ int s[2][512];
    int b = blockIdx.x, t = threadIdx.x;
    if (b < NROWT) {
        int i = b * 512 + t;
        int v = (i < N_NODES) ? deg[i] : 0;
        int incl = incl_scan512(v, t, s);
        if (i < N_NODES) row_excl[i] = incl - v;
        if (t == 511) rbsum[b] = incl;
    } else {
        int bb = b - NROWT;
        int i = bb * 512 + t;
        int v = (i < NHIST) ? histG[i] : 0;
        int incl = incl_scan512(v, t, s);
        if (i < NHIST) hist_excl[i] = incl - v;
        if (t == 511) hbsum[bb] = incl;
    }
}

__global__ __launch_bounds__(512) void k_scanB(int* __restrict__ rbsum,
                                               int* __restrict__ hbsum)
{
    __shared__ int s[2][512];
    int t = threadIdx.x;
    int* arr = (blockIdx.x == 0) ? rbsum : hbsum;
    int n    = (blockIdx.x == 0) ? NROWT : NHISTT;
    int v = (t < n) ? arr[t] : 0;
    int incl = incl_scan512(v, t, s);
    if (t < n) arr[t] = incl - v;   // exclusive, in place
}

__global__ __launch_bounds__(512) void k_scanC(
    const int* __restrict__ row_excl, const int* __restrict__ rbsum,
    int* __restrict__ row_ptr,
    const int* __restrict__ hist_excl, const int* __restrict__ hbsum,
    int* __restrict__ scanned)
{
    int b = blockIdx.x, t = threadIdx.x;
    if (b < NROWT) {
        int i = b * 512 + t;
        if (i < N_NODES) row_ptr[i] = row_excl[i] + rbsum[b];
        if (b == 0 && t == 0) row_ptr[N_NODES] = N_EDGES;
    } else {
        int bb = b - NROWT;
        int i = bb * 512 + t;
        if (i < NHIST) scanned[i] = hist_excl[i] + hbsum[bb];
    }
}

// --------------------------------------------------- scatter pass A (no atomics
// on global): each block owns exclusive (block,bucket) segments from the scan;
// LDS cursors only. Writes are sequential per segment -> full-line writeback.

__global__ __launch_bounds__(256) void k_scatterA(
    const int* __restrict__ rows, const int* __restrict__ cols,
    const float* __restrict__ ew, const int* __restrict__ scanned,
    uint2* __restrict__ tmp)
{
    __shared__ int cur[NBUCKET];
    int b = blockIdx.x, t = threadIdx.x;
    for (int i = t; i < NBUCKET; i += 256)
        cur[i] = scanned[(size_t)i * NBLKH + b];
    __syncthreads();
    int base = b * CHUNK;
    #pragma unroll 4
    for (int i = 0; i < CHUNK / 256; ++i) {
        int e = base + i * 256 + t;
        if (e < N_EDGES) {
            int r = rows[e];
            unsigned hv = (unsigned)__half_as_ushort(__float2half(ew[e]));
            unsigned pv = ((unsigned)cols[e] << 15) | (hv & 0x7fffu);
            int p = atomicAdd(&cur[r >> 7], 1);
            tmp[p] = make_uint2(pv, (unsigned)r);
        }
    }
}

// --------------------------------------------------- scatter pass B
// one block per bucket; per-row cursors in LDS; destination is the bucket's
// ~8KB contiguous CSR slice (L2-resident, full-line writeback).

__global__ __launch_bounds__(256) void k_passB(
    const int* __restrict__ row_ptr, const uint2* __restrict__ tmp,
    unsigned* __restrict__ ecw)
{
    __shared__ int cur[128];
    int b  = blockIdx.x;
    int r0 = b * 128;
    int t  = threadIdx.x;
    if (t < 128) {
        int rr = r0 + t;
        cur[t] = (rr < N_NODES) ? row_ptr[rr] : N_EDGES;
    }
    __syncthreads();
    int beg = row_ptr[r0];
    int rend = r0 + 128; if (rend > N_NODES) rend = N_NODES;
    int end = row_ptr[rend];
    for (int e = beg + t; e < end; e += 256) {
        uint2 v = tmp[e];
        int p = atomicAdd(&cur[v.y & 127], 1);
        ecw[p] = v.x;
    }
}

// ---------------------------------------------------------------- MFMA GEMM
// C[M x 128] = A[M x K] @ B[K x 128], bf16 MFMA 16x16x32, fp32 accumulate.
// BM=32 BN=128 BK=64, 256 threads = 4 waves. AMODE 0: A fp32 (convert while
// staging); AMODE 1: A bf16 row-major stride 128. OMODE 0: C bf16 row-major;
// OMODE 1: fp32 split at col 64 into C0/C1 with fused bias.

template<int AMODE, int OMODE>
__global__ __launch_bounds__(256) void k_gemm(
    int K, const float* __restrict__ A32, const unsigned short* __restrict__ A16,
    const unsigned short* __restrict__ Bpre,
    unsigned short* __restrict__ C16,
    float* __restrict__ C0, float* __restrict__ C1,
    const float* __restrict__ bias0, const float* __restrict__ bias1)
{
    __shared__ unsigned short As[2048];  // [rt2][kc8][m16][j8]
    __shared__ unsigned short Bs[8192];  // [nt8][kc8][n16][j8]

    const int t    = threadIdx.x;
    const int m0   = blockIdx.x * 32;
    const int lane = t & 63;
    const int w    = t >> 6;
    const int rt   = w & 1;
    const int ntb  = (w >> 1) * 4;
    const int fm   = lane & 15;
    const int q    = lane >> 4;
    const int K8   = K >> 3;

    f32x4 acc[4] = {};

    for (int kt = 0; kt < K; kt += 64) {
        {
            int r = t >> 3, kc = t & 7;
            int lo = ((r >> 4) * 8 + kc) * 128 + (r & 15) * 8;
            if (AMODE == 0) {
                const float* g = A32 + (size_t)(m0 + r) * K + kt + kc * 8;
                float4 a = *(const float4*)g;
                float4 b = *(const float4*)(g + 4);
                s16x8 v;
                v[0] = (short)f2bf(a.x); v[1] = (short)f2bf(a.y);
                v[2] = (short)f2bf(a.z); v[3] = (short)f2bf(a.w);
                v[4] = (short)f2bf(b.x); v[5] = (short)f2bf(b.y);
                v[6] = (short)f2bf(b.z); v[7] = (short)f2bf(b.w);
                *(s16x8*)&As[lo] = v;
            } else {
                const unsigned short* g = A16 + (size_t)(m0 + r) * 128 + kt + kc * 8;
                *(s16x8*)&As[lo] = *(const s16x8*)g;
            }
        }
        {
            int ktc = kt >> 3;
            #pragma unroll
            for (int i = 0; i < 4; ++i) {
                int c  = t + i * 256;
                int nt = c >> 7, kc = (c >> 4) & 7, m = c & 15;
                const unsigned short* g =
                    Bpre + ((size_t)(nt * K8 + ktc + kc) * 16 + m) * 8;
                *(s16x8*)&Bs[c * 8] = *(const s16x8*)g;
            }
        }
        __syncthreads();
        #pragma unroll
        for (int kk = 0; kk < 2; ++kk) {
            int kcq = kk * 4 + q;
            s16x8 a = *(const s16x8*)&As[(rt * 8 + kcq) * 128 + fm * 8];
            #pragma unroll
            for (int i = 0; i < 4; ++i) {
                s16x8 b = *(const s16x8*)&Bs[((ntb + i) * 8 + kcq) * 128 + fm * 8];
                acc[i] = __builtin_amdgcn_mfma_f32_16x16x32_bf16(a, b, acc[i], 0, 0, 0);
            }
        }
        __syncthreads();
    }

    // epilogue: C/D layout col=lane&15, row=q*4+reg
    #pragma unroll
    for (int i = 0; i < 4; ++i) {
        int col = (ntb + i) * 16 + fm;
        #pragma unroll
        for (int j = 0; j < 4; ++j) {
            int r = m0 + rt * 16 + q * 4 + j;
            float v = acc[i][j];
            if (OMODE == 0) {
                C16[(size_t)r * 128 + col] = f2bf(v);
            } else {
                if (col < 64) C0[(size_t)r * 64 + col]      = v + bias0[col];
                else          C1[(size_t)r * 64 + col - 64] = v + bias1[col - 64];
            }
        }
    }
}

// ---------------------------------------------------------------- SpMM gather
// out[row] = relu(bias + sum_e w_e * sup[col_e]); sup/out bf16, fp32 accum.
// One wave per row; lane-halves own edge parity (2 edges / load instr),
// 32 lanes x uint2 = 4 bf16 feats per lane; unroll 4 -> 8 gathers in flight.
// Cross-half combine via shfl_xor(32).

__global__ __launch_bounds__(256) void k_spmm(const int* __restrict__ row_ptr,
                                              const unsigned* __restrict__ ecw,
                                              const unsigned short* __restrict__ sup,
                                              const float* __restrict__ bias,
                                              unsigned short* __restrict__ out) {
    int wave = threadIdx.x >> 6;
    int lane = threadIdx.x & 63;
    int row  = blockIdx.x * 4 + wave;
    if (row >= N_NODES) return;
    int half = lane >> 5;          // edge parity
    int fl   = lane & 31;          // feats fl*4 .. fl*4+3

    int beg = row_ptr[row];
    int end = row_ptr[row + 1];
    float a0 = 0.f, a1 = 0.f, a2 = 0.f, a3 = 0.f;

    int n8 = beg + ((end - beg) & ~7);
    for (int e = beg; e < n8; e += 8) {
        unsigned q0 = ecw[e + 0 + half];
        unsigned q1 = ecw[e + 2 + half];
        unsigned q2 = ecw[e + 4 + half];
        unsigned q3 = ecw[e + 6 + half];
        uint2 v0 = *(const uint2*)(sup + (size_t)(q0 >> 15) * NHID + fl * 4);
        uint2 v1 = *(const uint2*)(sup + (size_t)(q1 >> 15) * NHID + fl * 4);
        uint2 v2 = *(const uint2*)(sup + (size_t)(q2 >> 15) * NHID + fl * 4);
        uint2 v3 = *(const uint2*)(sup + (size_t)(q3 >> 15) * NHID + fl * 4);
        float w0 = w15_decode(q0), w1 = w15_decode(q1);
        float w2 = w15_decode(q2), w3 = w15_decode(q3);
        a0 += w0 * bf2f((unsigned short)v0.x);
        a1 += w0 * bf2f((unsigned short)(v0.x >> 16));
        a2 += w0 * bf2f((unsigned short)v0.y);
        a3 += w0 * bf2f((unsigned short)(v0.y >> 16));
        a0 += w1 * bf2f((unsigned short)v1.x);
        a1 += w1 * bf2f((unsigned short)(v1.x >> 16));
        a2 += w1 * bf2f((unsigned short)v1.y);
        a3 += w1 * bf2f((unsigned short)(v1.y >> 16));
        a0 += w2 * bf2f((unsigned short)v2.x);
        a1 += w2 * bf2f((unsigned short)(v2.x >> 16));
        a2 += w2 * bf2f((unsigned short)v2.y);
        a3 += w2 * bf2f((unsigned short)(v2.y >> 16));
        a0 += w3 * bf2f((unsigned short)v3.x);
        a1 += w3 * bf2f((unsigned short)(v3.x >> 16));
        a2 += w3 * bf2f((unsigned short)v3.y);
        a3 += w3 * bf2f((unsigned short)(v3.y >> 16));
    }
    for (int e = n8; e < end; e += 2) {
        int ee = e + half;
        if (ee < end) {
            unsigned q = ecw[ee];
            uint2 v = *(const uint2*)(sup + (size_t)(q >> 15) * NHID + fl * 4);
            float w = w15_decode(q);
            a0 += w * bf2f((unsigned short)v.x);
            a1 += w * bf2f((unsigned short)(v.x >> 16));
            a2 += w * bf2f((unsigned short)v.y);
            a3 += w * bf2f((unsigned short)(v.y >> 16));
        }
    }
    a0 += __shfl_xor(a0, 32, 64);
    a1 += __shfl_xor(a1, 32, 64);
    a2 += __shfl_xor(a2, 32, 64);
    a3 += __shfl_xor(a3, 32, 64);

    if (half == 0) {
        float o0 = a0 + bias[fl * 4 + 0];
        float o1 = a1 + bias[fl * 4 + 1];
        float o2 = a2 + bias[fl * 4 + 2];
        float o3 = a3 + bias[fl * 4 + 3];
        o0 = o0 > 0.f ? o0 : 0.f;
        o1 = o1 > 0.f ? o1 : 0.f;
        o2 = o2 > 0.f ? o2 : 0.f;
        o3 = o3 > 0.f ? o3 : 0.f;
        uint2 pv;
        pv.x = (unsigned)f2bf(o0) | ((unsigned)f2bf(o1) << 16);
        pv.y = (unsigned)f2bf(o2) | ((unsigned)f2bf(o3) << 16);
        *(uint2*)(out + (size_t)row * NHID + fl * 4) = pv;
    }
}

// ---------------------------------------------------------------- launch

extern "C" void kernel_launch(void* const* d_in, const int* in_sizes, int n_in,
                              void* d_out, int out_size, void* d_ws, size_t ws_size,
                              hipStream_t stream) {
    const float* x     = (const float*)d_in[0];
    const int*   ei    = (const int*)  d_in[1];
    const float* ew    = (const float*)d_in[2];
    const float* gc1_w = (const float*)d_in[3];
    const float* gc1_b = (const float*)d_in[4];
    const float* gc2_w = (const float*)d_in[5];
    const float* gc2_b = (const float*)d_in[6];
    const float* mu_w  = (const float*)d_in[7];
    const float* mu_b  = (const float*)d_in[8];
    const float* lv_w  = (const float*)d_in[9];
    const float* lv_b  = (const float*)d_in[10];
    float* out = (float*)d_out;

    const int* rows = ei;
    const int* cols = ei + N_EDGES;

    char* p = (char*)d_ws;
    auto alloc = [&](size_t bytes) {
        char* r = p;
        p += (bytes + 255) & ~(size_t)255;
        return r;
    };
    int*      deg       = (int*)     alloc((size_t)N_NODES * 4);
    int*      row_excl  = (int*)     alloc((size_t)N_NODES * 4);
    int*      row_ptr   = (int*)     alloc((size_t)(N_NODES + 1) * 4);
    int*      rbsum     = (int*)     alloc((size_t)NROWT * 4);
    int*      histG     = (int*)     alloc((size_t)NHIST * 4);
    int*      hist_excl = (int*)     alloc((size_t)NHIST * 4);
    int*      hbsum     = (int*)     alloc((size_t)NHISTT * 4);
    int*      scanned   = (int*)     alloc((size_t)NHIST * 4);
    unsigned* ecw       = (unsigned*)alloc((size_t)N_EDGES * 4);
    uint2*    tmp       = (uint2*)   alloc((size_t)N_EDGES * 8);
    unsigned short* w1p    = (unsigned short*)alloc((size_t)NFEAT * NHID * 2);
    unsigned short* w2p    = (unsigned short*)alloc((size_t)NHID * NHID * 2);
    unsigned short* w3p    = (unsigned short*)alloc((size_t)NHID * NHID * 2);
    unsigned short* bufSup = (unsigned short*)alloc((size_t)N_NODES * NHID * 2);
    unsigned short* bufH   = (unsigned short*)alloc((size_t)N_NODES * NHID * 2);
    (void)ws_size; (void)n_in; (void)in_sizes; (void)out_size;

    hipMemsetAsync(deg, 0, (size_t)N_NODES * 4, stream);
    // deg count + coarse histogram || weight prep
    k_pre<<<NBLKH + 32, 256, 0, stream>>>(rows, deg, histG,
                                          gc1_w, w1p, gc2_w, w2p, mu_w, lv_w, w3p);
    // scans: rows (196 tiles) + hist (300 tiles)
    k_scanA<<<NROWT + NHISTT, 512, 0, stream>>>(deg, row_excl, rbsum,
                                                histG, hist_excl, hbsum);
    k_scanB<<<2, 512, 0, stream>>>(rbsum, hbsum);
    k_scanC<<<NROWT + NHISTT, 512, 0, stream>>>(row_excl, rbsum, row_ptr,
                                                hist_excl, hbsum, scanned);
    // two-pass reorder, no global atomics in pass A
    k_scatterA<<<NBLKH, 256, 0, stream>>>(rows, cols, ew, scanned, tmp);
    k_passB<<<NBUCKET, 256, 0, stream>>>(row_ptr, tmp, ecw);

    // gc1
    k_gemm<0, 0><<<N_NODES / 32, 256, 0, stream>>>(NFEAT, x, nullptr, w1p,
                                                   bufSup, nullptr, nullptr, nullptr, nullptr);
    k_spmm<<<N_NODES / 4, 256, 0, stream>>>(row_ptr, ecw, bufSup, gc1_b, bufH);
    // gc2
    k_gemm<1, 0><<<N_NODES / 32, 256, 0, stream>>>(NHID, nullptr, bufH, w2p,
                                                   bufSup, nullptr, nullptr, nullptr, nullptr);
    k_spmm<<<N_NODES / 4, 256, 0, stream>>>(row_ptr, ecw, bufSup, gc2_b, bufH);
    // mu / log_var fused projection
    k_gemm<1, 1><<<N_NODES / 32, 256, 0, stream>>>(NHID, nullptr, bufH, w3p,
                                                   nullptr, out, out + (size_t)N_NODES * LATENT,
                                                   mu_b, lv_b);
}